// Round 6
// baseline (840.032 us; speedup 1.0000x reference)
//
#include <hip/hip_runtime.h>
#include <stdint.h>

// ---------------------------------------------------------------------------
// T3KAN pipeline on MI355X. ALL inputs and the output are float32.
//
//  0. split_kernel    : fp32 -> (hi,lo) bf16 for x, Wq, Wk, Wv, Wo
//  1. eta_kernel      : lr = sigmoid(x . lrW_h + b_h)/64 * gs[m]  -> eta fp32
//  2. qkv_rope_kernel : QKV = x @ W^T, 3-pass split-bf16 MFMA, 128x128 LDS
//                       tiles staged via vector-load + ds_write (NOT
//                       global_load_lds: R4 showed it defeats L2 reuse here)
//                       + fused RoPE epilogue.
//  3. scan_kernel     : 128-step TTT scan (sparse uniform-knot B-spline)
//     R6: batched cumsum LDS reads (kills 16x serial ds_read latency),
//         single fused 6-value K-side reduction (one shuffle phase, not two),
//         hw-native exp2/rcp/rsq in the hot loop.
//  4. ln_kernel       : final LayerNorm -> (hi,lo) bf16
//  5. out_gemm_kernel : ln @ Wo^T, same tiled split GEMM -> fp32
// ---------------------------------------------------------------------------

typedef unsigned short ushort_t;
typedef short bf16x8 __attribute__((ext_vector_type(8)));
typedef float f32x4 __attribute__((ext_vector_type(4)));

// LDS tile row stride: 40 ushorts = 80 B -> bank stride 20 -> 2-way lane
// aliasing on ds_read_b128 (free per m136), vs 64 B stride's 8-way.
#define LSTRIDE 40

__device__ __forceinline__ float bf2f(ushort_t u) {
    union { uint32_t i; float f; } v; v.i = ((uint32_t)u) << 16; return v.f;
}
__device__ __forceinline__ ushort_t f2bf(float f) {   // RNE fp32->bf16
    union { float f; uint32_t i; } v; v.f = f;
    uint32_t r = v.i + 0x7FFFu + ((v.i >> 16) & 1u);
    return (ushort_t)(r >> 16);
}
__device__ __forceinline__ float silu(float x) { return x / (1.0f + expf(-x)); }

// fast (hw-native, ~1 ulp) variants for the scan hot loop
__device__ __forceinline__ float fast_silu(float x) {
    const float e = __builtin_amdgcn_exp2f(-1.4426950408889634f * x);
    return x * __builtin_amdgcn_rcpf(1.0f + e);
}
__device__ __forceinline__ float fast_rsq(float x) {
    return __builtin_amdgcn_rsqf(x);
}

__device__ __forceinline__ void wave_reduce2(float& a, float& b) {
#pragma unroll
    for (int off = 32; off > 0; off >>= 1) {
        a += __shfl_xor(a, off, 64);
        b += __shfl_xor(b, off, 64);
    }
}

// ---------------------------------------------------------------------------
// Sparse degree-3 B-spline on UNIFORM knots linspace(-1,1,15), delta=1/7.
// 4 nonzero basis values; j-slot 11 is a dummy zero. Zero divides.
// ---------------------------------------------------------------------------
struct Bas4 { float n[4]; int j[4]; };
__device__ __forceinline__ Bas4 bspline4(float x) {
    const float DELTA = 0.14285714285714285f;  // 1/7
    const float xp1 = x + 1.0f;
    const float fi = floorf(xp1 * 7.0f);
    const bool valid = (fi >= 0.0f) && (fi <= 13.0f);
    const float fic = valid ? fi : 0.0f;
    const float left1  = xp1 - fic * DELTA;
    const float left2  = xp1 - (fic - 1.0f) * DELTA;
    const float left3  = xp1 - (fic - 2.0f) * DELTA;
    const float right1 = (fic + 1.0f) * DELTA - xp1;
    const float right2 = (fic + 2.0f) * DELTA - xp1;
    const float right3 = (fic + 3.0f) * DELTA - xp1;
    float N0, N1, N2, N3, saved, temp;
    temp = 7.0f;
    N0 = right1 * temp;
    N1 = left1 * temp;
    temp = N0 * 3.5f;
    N0 = right1 * temp; saved = left2 * temp;
    temp = N1 * 3.5f;
    N1 = fmaf(right2, temp, saved);
    N2 = left1 * temp;
    const float inv3 = 2.3333333333333335f;
    temp = N0 * inv3;
    N0 = right1 * temp; saved = left3 * temp;
    temp = N1 * inv3;
    N1 = fmaf(right2, temp, saved); saved = left2 * temp;
    temp = N2 * inv3;
    N2 = fmaf(right3, temp, saved);
    N3 = left1 * temp;

    Bas4 r;
    const int i = (int)fic;
    const float nv[4] = {N0, N1, N2, N3};
#pragma unroll
    for (int t = 0; t < 4; ++t) {
        const int j = i - 3 + t;
        const bool ok = valid && (j >= 0) && (j <= 10);
        r.n[t] = ok ? nv[t] : 0.0f;
        r.j[t] = ok ? j : 11;
    }
    return r;
}

// ---------------------------------------------------------------------------
// 0. fp32 -> (hi, lo) bf16 split. n4 = element_count / 4.
// ---------------------------------------------------------------------------
__global__ __launch_bounds__(256) void split_kernel(
    const float* __restrict__ in, ushort_t* __restrict__ hi,
    ushort_t* __restrict__ lo, int n4)
{
    const int i = blockIdx.x * 256 + threadIdx.x;
    if (i >= n4) return;
    const float4 f = reinterpret_cast<const float4*>(in)[i];
    const ushort_t h0 = f2bf(f.x), h1 = f2bf(f.y), h2 = f2bf(f.z), h3 = f2bf(f.w);
    ushort4 hv; hv.x = h0; hv.y = h1; hv.z = h2; hv.w = h3;
    ushort4 lv;
    lv.x = f2bf(f.x - bf2f(h0)); lv.y = f2bf(f.y - bf2f(h1));
    lv.z = f2bf(f.z - bf2f(h2)); lv.w = f2bf(f.w - bf2f(h3));
    reinterpret_cast<ushort4*>(hi)[i] = hv;
    reinterpret_cast<ushort4*>(lo)[i] = lv;
}

// ---------------------------------------------------------------------------
// 1. eta: one wave per (b,s) row, loops h=0..15. eta[((b*16+h)*128+n)*16+m]
// ---------------------------------------------------------------------------
__global__ __launch_bounds__(256) void eta_kernel(
    const float* __restrict__ x, const float* __restrict__ lrW,
    const float* __restrict__ lrb, const float* __restrict__ gsc,
    float* __restrict__ eta)
{
    const int row = blockIdx.x * 4 + (threadIdx.x >> 6);
    const int lane = threadIdx.x & 63;
    float xv[16];
#pragma unroll
    for (int i = 0; i < 16; ++i) xv[i] = x[(size_t)row * 1024 + lane + i * 64];
    const int b = row >> 11, s = row & 2047, n = s >> 4, m = s & 15;
    const float gs = fmaxf(1.0f / (float)(m + 1) + gsc[m], 0.0f);
    for (int h = 0; h < 16; ++h) {
        float acc = 0.0f;
#pragma unroll
        for (int i = 0; i < 16; ++i) acc += xv[i] * lrW[h * 1024 + lane + i * 64];
#pragma unroll
        for (int off = 32; off > 0; off >>= 1) acc += __shfl_xor(acc, off, 64);
        if (lane == 0) {
            float sig = 1.0f / (1.0f + expf(-(acc + lrb[h])));
            eta[(((size_t)(b * 16 + h)) * 128 + n) * 16 + m] = (sig / 64.0f) * gs;
        }
    }
}

// ---------------------------------------------------------------------------
// Shared GEMM body: 512 threads = 8 waves (2 row-halves x 4 col-quarters),
// block tile 128x128, BK=32, LDS staged via vector loads + ds_write_b128,
// one-tile register prefetch. Wave tile 64x32 -> acc[4][2], 24 MFMA per k0.
// ---------------------------------------------------------------------------
#define GEMM_TILE_BODY(Ah_g, Al_g, Bh_g, Bl_g, rowbase, colb)                  \
    __shared__ __align__(16) ushort_t Ash[128 * LSTRIDE];                      \
    __shared__ __align__(16) ushort_t Asl[128 * LSTRIDE];                      \
    __shared__ __align__(16) ushort_t Bsh[128 * LSTRIDE];                      \
    __shared__ __align__(16) ushort_t Bsl[128 * LSTRIDE];                      \
    const int tid = threadIdx.x;                                               \
    const int wv = tid >> 6, ln = tid & 63;                                    \
    const int l15 = ln & 15, lq = ln >> 4;                                     \
    const int wm = wv >> 2, wn = wv & 3;                                       \
    const int srow = tid >> 2;               /* 0..127 */                      \
    const int skseg = (tid & 3) * 8;         /* 0,8,16,24 */                   \
    const ushort_t* gA_h = (Ah_g) + (size_t)((rowbase) + srow) * 1024 + skseg; \
    const ushort_t* gA_l = (Al_g) + (size_t)((rowbase) + srow) * 1024 + skseg; \
    const ushort_t* gB_h = (Bh_g) + (size_t)((colb) + srow) * 1024 + skseg;    \
    const ushort_t* gB_l = (Bl_g) + (size_t)((colb) + srow) * 1024 + skseg;    \
    const int sw = srow * LSTRIDE + skseg;                                     \
    f32x4 acc[4][2] = {};                                                      \
    bf16x8 rAh = *reinterpret_cast<const bf16x8*>(gA_h);                       \
    bf16x8 rAl = *reinterpret_cast<const bf16x8*>(gA_l);                       \
    bf16x8 rBh = *reinterpret_cast<const bf16x8*>(gB_h);                       \
    bf16x8 rBl = *reinterpret_cast<const bf16x8*>(gB_l);                       \
    for (int k0 = 0; k0 < 1024; k0 += 32) {                                    \
        *reinterpret_cast<bf16x8*>(&Ash[sw]) = rAh;                            \
        *reinterpret_cast<bf16x8*>(&Asl[sw]) = rAl;                            \
        *reinterpret_cast<bf16x8*>(&Bsh[sw]) = rBh;                            \
        *reinterpret_cast<bf16x8*>(&Bsl[sw]) = rBl;                            \
        __syncthreads();                                                       \
        const int kn = k0 + 32;                                                \
        if (kn < 1024) {                                                       \
            rAh = *reinterpret_cast<const bf16x8*>(gA_h + kn);                 \
            rAl = *reinterpret_cast<const bf16x8*>(gA_l + kn);                 \
            rBh = *reinterpret_cast<const bf16x8*>(gB_h + kn);                 \
            rBl = *reinterpret_cast<const bf16x8*>(gB_l + kn);                 \
        }                                                                      \
        bf16x8 bh[2], bl[2];                                                   \
        _Pragma("unroll")                                                      \
        for (int u = 0; u < 2; ++u) {                                          \
            const int br = (wn * 32 + u * 16 + l15) * LSTRIDE + lq * 8;        \
            bh[u] = *reinterpret_cast<const bf16x8*>(&Bsh[br]);                \
            bl[u] = *reinterpret_cast<const bf16x8*>(&Bsl[br]);                \
        }                                                                      \
        _Pragma("unroll")                                                      \
        for (int t = 0; t < 4; ++t) {                                          \
            const int ar = (wm * 64 + t * 16 + l15) * LSTRIDE + lq * 8;        \
            const bf16x8 ah = *reinterpret_cast<const bf16x8*>(&Ash[ar]);      \
            const bf16x8 al = *reinterpret_cast<const bf16x8*>(&Asl[ar]);      \
            _Pragma("unroll")                                                  \
            for (int u = 0; u < 2; ++u) {                                      \
                acc[t][u] = __builtin_amdgcn_mfma_f32_16x16x32_bf16(ah, bh[u], acc[t][u], 0, 0, 0); \
                acc[t][u] = __builtin_amdgcn_mfma_f32_16x16x32_bf16(ah, bl[u], acc[t][u], 0, 0, 0); \
                acc[t][u] = __builtin_amdgcn_mfma_f32_16x16x32_bf16(al, bh[u], acc[t][u], 0, 0, 0); \
            }                                                                  \
        }                                                                      \
        __syncthreads();                                                       \
    }

// ---------------------------------------------------------------------------
// 2. QKV GEMM + RoPE. grid (8192/128=64, 3*1024/128=24), 512 threads.
// ---------------------------------------------------------------------------
__global__ __launch_bounds__(512) void qkv_rope_kernel(
    const ushort_t* __restrict__ xh, const ushort_t* __restrict__ xl,
    const ushort_t* __restrict__ Wqh, const ushort_t* __restrict__ Wql,
    const ushort_t* __restrict__ Wkh, const ushort_t* __restrict__ Wkl,
    const ushort_t* __restrict__ Wvh, const ushort_t* __restrict__ Wvl,
    const float* __restrict__ posf,
    float* __restrict__ Qb, float* __restrict__ Kb, float* __restrict__ Vb)
{
    const int rowbase = blockIdx.x * 128;
    const int colbase = blockIdx.y * 128;
    const int sel = colbase >> 10;                 // 0=Q 1=K 2=V (uniform)
    const ushort_t* WBh = (sel == 0) ? Wqh : (sel == 1) ? Wkh : Wvh;
    const ushort_t* WBl = (sel == 0) ? Wql : (sel == 1) ? Wkl : Wvl;
    float* dst = (sel == 0) ? Qb : (sel == 1) ? Kb : Vb;
    const int colm = colbase & 1023;

    GEMM_TILE_BODY(xh, xl, WBh, WBl, rowbase, colm)

    // epilogue: RoPE + scatter to [b][h][n][m][d]
#pragma unroll
    for (int t = 0; t < 4; ++t)
#pragma unroll
        for (int u = 0; u < 2; ++u) {
            const int col = colm + wn * 32 + u * 16 + l15;  // col in matrix
            const int d = col & 63, h = col >> 6;
            const int angidx = d >> 1;
            const int odd = d & 1;
#pragma unroll
            for (int r = 0; r < 4; ++r) {
                const int row = rowbase + wm * 64 + t * 16 + lq * 4 + r;
                const int b = row >> 11, s = row & 2047;
                const float ang = posf[s * 32 + angidx];
                const float c = cosf(ang), sn = sinf(ang);
                const float own = acc[t][u][r];
                const float partner = __shfl_xor(own, 1, 64);
                const float res = odd ? (partner * sn + own * c)
                                      : (own * c - partner * sn);
                const int n = s >> 4, m = s & 15;
                dst[(((size_t)(b * 16 + h)) * 128 + n) * 1024 + m * 64 + d] = res;
            }
        }
}

// ---------------------------------------------------------------------------
// 3. TTT scan: 64 blocks (one per (b,h)), 1024 threads (wave=m, lane=d).
//    R6: batched cumsum loads; fused single-phase 6-value K reduction.
//    Algebra: gxh = gam^2*xhat + E, E = gam*(bet - (vf-kf));
//      t1 = sum(gxh)     = rstd*(C - mu*G) + SE
//      t2 = sum(gxh*xhat)= rstd^2*(D - 2mu*C + mu^2*G) + rstd*(F - mu*SE)
//    with C=sum(gam^2 zk), D=sum(gam^2 zk^2), SE=sum(E), F=sum(E zk),
//    G=sum(gam^2) (precomputed once).
// ---------------------------------------------------------------------------
__global__ __launch_bounds__(1024) void scan_kernel(
    const float* __restrict__ Qb, const float* __restrict__ Kb,
    const float* __restrict__ Vb, const float* __restrict__ eta,
    const float* __restrict__ tg, const float* __restrict__ tb,
    const float* __restrict__ coeff, float* __restrict__ out_pre)
{
    __shared__ float Wl[12 * 64];        // rows 0..10 = W, row 11 = zeros
    __shared__ float cum[16 * 12 * 64];  // 48 KiB

    const int tid = threadIdx.x;
    const int m = tid >> 6, d = tid & 63;
    const int b = blockIdx.x >> 4, h = blockIdx.x & 15;

    const float gam = tg[h * 64 + d];
    const float bet = tb[h * 64 + d];
    const float gam2 = gam * gam;
    float G = gam2;                       // sum over d of gam^2 (per-wave)
#pragma unroll
    for (int off = 32; off > 0; off >>= 1) G += __shfl_xor(G, off, 64);

    if (tid < 768) Wl[tid] = (tid < 704) ? coeff[h * 704 + tid] : 0.0f;
    __syncthreads();

    const size_t base = ((size_t)(b * 16 + h)) * 131072;
    const float* Qp = Qb + base;
    const float* Kp = Kb + base;
    const float* Vp = Vb + base;
    const float* ep = eta + ((size_t)(b * 16 + h)) * 2048;

    float kf = Kp[tid], vf = Vp[tid], qf = Qp[tid], ei = ep[m];

    for (int n = 0; n < 128; ++n) {
        const int n1 = (n < 127) ? n + 1 : n;
        const float kfN = Kp[n1 * 1024 + tid];
        const float vfN = Vp[n1 * 1024 + tid];
        const float qfN = Qp[n1 * 1024 + tid];
        const float eiN = ep[n1 * 16 + m];

        // ---- K side ----
        const Bas4 bk = bspline4(kf);
        float zk = fast_silu(kf);
#pragma unroll
        for (int t = 0; t < 4; ++t)
            zk = fmaf(bk.n[t], Wl[bk.j[t] * 64 + d], zk);

        const float E = gam * (bet - (vf - kf));
        float r0 = zk, r1 = zk * zk, r2 = gam2 * zk, r3 = gam2 * zk * zk,
              r4 = E, r5 = E * zk;
#pragma unroll
        for (int off = 32; off > 0; off >>= 1) {
            r0 += __shfl_xor(r0, off, 64);
            r1 += __shfl_xor(r1, off, 64);
            r2 += __shfl_xor(r2, off, 64);
            r3 += __shfl_xor(r3, off, 64);
            r4 += __shfl_xor(r4, off, 64);
            r5 += __shfl_xor(r5, off, 64);
        }
        const float mu = r0 * (1.0f / 64.0f);
        const float var = r1 * (1.0f / 64.0f) - mu * mu;
        const float rstd = fast_rsq(var + 1e-6f);
        const float xhat = (zk - mu) * rstd;
        const float gxh = gam2 * xhat + E;
        const float t1 = rstd * (r2 - mu * G) + r4;
        const float t2 = rstd * rstd * (r3 - 2.0f * mu * r2 + mu * mu * G)
                       + rstd * (r5 - mu * r4);
        const float gz = (gxh - t1 * (1.0f / 64.0f) - xhat * (t2 * (1.0f / 64.0f))) * rstd;

        // ---- tok scatter: zero 12 slots then overwrite the 4 live ones ----
        const float tokf = ei * gz;
#pragma unroll
        for (int j = 0; j < 12; ++j) cum[m * 768 + j * 64 + d] = 0.0f;
#pragma unroll
        for (int t = 0; t < 4; ++t)
            cum[m * 768 + bk.j[t] * 64 + d] = tokf * bk.n[t];
        __syncthreads();

        // ---- in-place U = W - cumsum, batched loads (one latency, not 16) --
        if (tid < 704) {
            float v[16];
#pragma unroll
            for (int mm = 0; mm < 16; ++mm) v[mm] = cum[mm * 768 + tid];
            float a = Wl[tid];
#pragma unroll
            for (int mm = 0; mm < 16; ++mm) {
                a -= v[mm];
                cum[mm * 768 + tid] = a;
            }
            Wl[tid] = a;
        }
        __syncthreads();

        // ---- Q side ----
        const Bas4 bq = bspline4(qf);
        float zq = fast_silu(qf);
#pragma unroll
        for (int t = 0; t < 4; ++t)
            zq = fmaf(bq.n[t], cum[m * 768 + bq.j[t] * 64 + d], zq);

        float u1 = zq, u2 = zq * zq;
        wave_reduce2(u1, u2);
        const float mu2 = u1 * (1.0f / 64.0f);
        const float var2 = u2 * (1.0f / 64.0f) - mu2 * mu2;
        const float rstd2 = fast_rsq(var2 + 1e-6f);
        const float y = qf + gam * (zq - mu2) * rstd2 + bet;
        out_pre[((size_t)b * 2048 + n * 16 + m) * 1024 + h * 64 + d] = y;

        __syncthreads();
        kf = kfN; vf = vfN; qf = qfN; ei = eiN;
    }
}

// ---------------------------------------------------------------------------
// 4. Final LayerNorm over DIM=1024 -> (hi, lo) bf16 for the split out-GEMM.
// ---------------------------------------------------------------------------
__global__ __launch_bounds__(256) void ln_kernel(
    const float* __restrict__ in, const float* __restrict__ pw,
    const float* __restrict__ pb, ushort_t* __restrict__ hi,
    ushort_t* __restrict__ lo)
{
    const int row = blockIdx.x * 4 + (threadIdx.x >> 6);
    const int lane = threadIdx.x & 63;
    const float* r = in + (size_t)row * 1024;
    float v[16];
    float s1 = 0.0f, s2 = 0.0f;
#pragma unroll
    for (int i = 0; i < 16; ++i) {
        v[i] = r[lane + i * 64];
        s1 += v[i];
        s2 += v[i] * v[i];
    }
    wave_reduce2(s1, s2);
    const float mu = s1 * (1.0f / 1024.0f);
    const float var = s2 * (1.0f / 1024.0f) - mu * mu;
    const float rstd = rsqrtf(var + 1e-6f);
#pragma unroll
    for (int i = 0; i < 16; ++i) {
        const int c = lane + i * 64;
        const float o = (v[i] - mu) * rstd * pw[c] + pb[c];
        const ushort_t h = f2bf(o);
        hi[(size_t)row * 1024 + c] = h;
        lo[(size_t)row * 1024 + c] = f2bf(o - bf2f(h));
    }
}

// ---------------------------------------------------------------------------
// 5. Output GEMM: same skeleton; plain fp32 epilogue. grid (64, 8).
// ---------------------------------------------------------------------------
__global__ __launch_bounds__(512) void out_gemm_kernel(
    const ushort_t* __restrict__ Ahg, const ushort_t* __restrict__ Alg,
    const ushort_t* __restrict__ Bhg, const ushort_t* __restrict__ Blg,
    float* __restrict__ out)
{
    const int rowbase = blockIdx.x * 128;
    const int colbase = blockIdx.y * 128;

    GEMM_TILE_BODY(Ahg, Alg, Bhg, Blg, rowbase, colbase)

#pragma unroll
    for (int t = 0; t < 4; ++t)
#pragma unroll
        for (int u = 0; u < 2; ++u) {
            const int col = colbase + wn * 32 + u * 16 + l15;
#pragma unroll
            for (int r = 0; r < 4; ++r) {
                const int row = rowbase + wm * 64 + t * 16 + lq * 4 + r;
                out[(size_t)row * 1024 + col] = acc[t][u][r];
            }
        }
}

// ---------------------------------------------------------------------------
extern "C" void kernel_launch(void* const* d_in, const int* in_sizes, int n_in,
                              void* d_out, int out_size, void* d_ws, size_t ws_size,
                              hipStream_t stream) {
    const float* x    = (const float*)d_in[0];
    const float* posf = (const float*)d_in[1];
    const float* Wq   = (const float*)d_in[2];
    const float* Wk   = (const float*)d_in[3];
    const float* Wv   = (const float*)d_in[4];
    const float* Wo   = (const float*)d_in[5];
    const float* lrW  = (const float*)d_in[6];
    const float* lrb  = (const float*)d_in[7];
    const float* gsc  = (const float*)d_in[8];
    const float* tg   = (const float*)d_in[9];
    const float* tb   = (const float*)d_in[10];
    const float* pw   = (const float*)d_in[11];
    const float* pb   = (const float*)d_in[12];
    const float* coeff= (const float*)d_in[13];
    // d_in[14] = knots: uniform linspace(-1,1,15); closed-form in scan.

    char* ws = (char*)d_ws;
    float*    Qb   = (float*)(ws);                      // 32 MB [dead after scan]
    float*    Kb   = (float*)(ws + 33554432);           // 32 MB [dead after scan]
    float*    Vb   = (float*)(ws + 67108864);           // 32 MB
    ushort_t* xh   = (ushort_t*)(ws + 100663296);       // 16 MB [dead after qkv]
    ushort_t* xl   = (ushort_t*)(ws + 117440512);       // 16 MB
    float*    outp = (float*)(ws + 100663296);          // 32 MB (aliases xh+xl)
    float*    eta  = (float*)(ws + 134217728);          // 0.5 MB
    ushort_t* Wqh  = (ushort_t*)(ws + 134742016);       // 2 MB each
    ushort_t* Wql  = (ushort_t*)(ws + 136839168);
    ushort_t* Wkh  = (ushort_t*)(ws + 138936320);
    ushort_t* Wkl  = (ushort_t*)(ws + 141033472);
    ushort_t* Wvh  = (ushort_t*)(ws + 143130624);
    ushort_t* Wvl  = (ushort_t*)(ws + 145227776);
    ushort_t* Woh  = (ushort_t*)(ws + 147324928);
    ushort_t* Wol  = (ushort_t*)(ws + 149422080);       // end 151519232
    ushort_t* lnh  = (ushort_t*)(ws);                   // aliases Qb (dead)
    ushort_t* lnl  = (ushort_t*)(ws + 16777216);

    split_kernel<<<8192, 256, 0, stream>>>(x,  xh,  xl,  2097152);
    split_kernel<<<1024, 256, 0, stream>>>(Wq, Wqh, Wql, 262144);
    split_kernel<<<1024, 256, 0, stream>>>(Wk, Wkh, Wkl, 262144);
    split_kernel<<<1024, 256, 0, stream>>>(Wv, Wvh, Wvl, 262144);
    split_kernel<<<1024, 256, 0, stream>>>(Wo, Woh, Wol, 262144);
    eta_kernel<<<2048, 256, 0, stream>>>(x, lrW, lrb, gsc, eta);
    qkv_rope_kernel<<<dim3(64, 24), 512, 0, stream>>>(xh, xl, Wqh, Wql, Wkh, Wkl,
                                                      Wvh, Wvl, posf, Qb, Kb, Vb);
    scan_kernel<<<64, 1024, 0, stream>>>(Qb, Kb, Vb, eta, tg, tb, coeff, outp);
    ln_kernel<<<2048, 256, 0, stream>>>(outp, pw, pb, lnh, lnl);
    out_gemm_kernel<<<dim3(64, 8), 512, 0, stream>>>(lnh, lnl, Woh, Wol, (float*)d_out);
}

// Round 8
// 662.854 us; speedup vs baseline: 1.2673x; 1.2673x over previous
//
#include <hip/hip_runtime.h>
#include <stdint.h>

// ---------------------------------------------------------------------------
// T3KAN pipeline on MI355X. ALL inputs and the output are float32.
//
//  0. split_kernel    : fp32 -> (hi,lo) bf16 for x, Wq, Wk, Wv, Wo
//  1. eta_kernel      : lr = sigmoid(x . lrW_h + b_h)/64 * gs[m]  -> eta fp32
//  2. qkv_rope_kernel : QKV = x @ W^T, 3-pass split-bf16 MFMA, 128x128 LDS
//                       tiles staged via vector-load + ds_write + RoPE
//  3. scan_kernel     : 128-step TTT scan. R7/R8: scan is LDS-PIPE bound
//                       (R6 census: ~1300 LDS wave-instrs/step). DPP-based
//                       wave reductions (1 ds_swizzle per value instead of 6)
//                       + float4 cumsum phase. R8 fixes the update_dpp
//                       immediate-operand constraint via template ctrl.
//  4. ln_kernel       : final LayerNorm -> (hi,lo) bf16
//  5. out_gemm_kernel : ln @ Wo^T, same tiled split GEMM -> fp32
// ---------------------------------------------------------------------------

typedef unsigned short ushort_t;
typedef short bf16x8 __attribute__((ext_vector_type(8)));
typedef float f32x4 __attribute__((ext_vector_type(4)));

#define LSTRIDE 40

__device__ __forceinline__ float bf2f(ushort_t u) {
    union { uint32_t i; float f; } v; v.i = ((uint32_t)u) << 16; return v.f;
}
__device__ __forceinline__ ushort_t f2bf(float f) {   // RNE fp32->bf16
    union { float f; uint32_t i; } v; v.f = f;
    uint32_t r = v.i + 0x7FFFu + ((v.i >> 16) & 1u);
    return (ushort_t)(r >> 16);
}
__device__ __forceinline__ float silu(float x) { return x / (1.0f + expf(-x)); }

__device__ __forceinline__ float fast_silu(float x) {
    const float e = __builtin_amdgcn_exp2f(-1.4426950408889634f * x);
    return x * __builtin_amdgcn_rcpf(1.0f + e);
}
__device__ __forceinline__ float fast_rsq(float x) {
    return __builtin_amdgcn_rsqf(x);
}

// ---------------------------------------------------------------------------
// VALU (DPP) wave-sum: xor1/2/4/8 on the vector pipe, one ds_swizzle for
// xor16, readlane pair + add for the 32/64 halves. LDS ops per value: 1
// (vs 6 for shfl_xor butterflies). Valid because after each stage all
// lanes of the group hold identical partial sums (mirror == xor for sums).
// ctrl must be an ICE -> template parameter.
// ---------------------------------------------------------------------------
template <int CTRL>
__device__ __forceinline__ float dpp_add(float v) {
    int p = __builtin_amdgcn_update_dpp(0, __float_as_int(v), CTRL, 0xF, 0xF, false);
    return v + __int_as_float(p);
}
__device__ __forceinline__ float wave_sum(float v) {
    v = dpp_add<0xB1>(v);   // quad_perm [1,0,3,2]  : xor1
    v = dpp_add<0x4E>(v);   // quad_perm [2,3,0,1]  : xor2
    v = dpp_add<0x141>(v);  // row_half_mirror      : xor4-equiv
    v = dpp_add<0x140>(v);  // row_mirror           : xor8-equiv
    int s = __builtin_amdgcn_ds_swizzle(__float_as_int(v), 0x401F); // xor16
    v = v + __int_as_float(s);
    const float a = __int_as_float(__builtin_amdgcn_readlane(__float_as_int(v), 0));
    const float b = __int_as_float(__builtin_amdgcn_readlane(__float_as_int(v), 32));
    return a + b;           // uniform across the wave
}

// ---------------------------------------------------------------------------
// Sparse degree-3 B-spline on UNIFORM knots linspace(-1,1,15), delta=1/7.
// ---------------------------------------------------------------------------
struct Bas4 { float n[4]; int j[4]; };
__device__ __forceinline__ Bas4 bspline4(float x) {
    const float DELTA = 0.14285714285714285f;  // 1/7
    const float xp1 = x + 1.0f;
    const float fi = floorf(xp1 * 7.0f);
    const bool valid = (fi >= 0.0f) && (fi <= 13.0f);
    const float fic = valid ? fi : 0.0f;
    const float left1  = xp1 - fic * DELTA;
    const float left2  = xp1 - (fic - 1.0f) * DELTA;
    const float left3  = xp1 - (fic - 2.0f) * DELTA;
    const float right1 = (fic + 1.0f) * DELTA - xp1;
    const float right2 = (fic + 2.0f) * DELTA - xp1;
    const float right3 = (fic + 3.0f) * DELTA - xp1;
    float N0, N1, N2, N3, saved, temp;
    temp = 7.0f;
    N0 = right1 * temp;
    N1 = left1 * temp;
    temp = N0 * 3.5f;
    N0 = right1 * temp; saved = left2 * temp;
    temp = N1 * 3.5f;
    N1 = fmaf(right2, temp, saved);
    N2 = left1 * temp;
    const float inv3 = 2.3333333333333335f;
    temp = N0 * inv3;
    N0 = right1 * temp; saved = left3 * temp;
    temp = N1 * inv3;
    N1 = fmaf(right2, temp, saved); saved = left2 * temp;
    temp = N2 * inv3;
    N2 = fmaf(right3, temp, saved);
    N3 = left1 * temp;

    Bas4 r;
    const int i = (int)fic;
    const float nv[4] = {N0, N1, N2, N3};
#pragma unroll
    for (int t = 0; t < 4; ++t) {
        const int j = i - 3 + t;
        const bool ok = valid && (j >= 0) && (j <= 10);
        r.n[t] = ok ? nv[t] : 0.0f;
        r.j[t] = ok ? j : 11;
    }
    return r;
}

// ---------------------------------------------------------------------------
// 0. fp32 -> (hi, lo) bf16 split. n4 = element_count / 4.
// ---------------------------------------------------------------------------
__global__ __launch_bounds__(256) void split_kernel(
    const float* __restrict__ in, ushort_t* __restrict__ hi,
    ushort_t* __restrict__ lo, int n4)
{
    const int i = blockIdx.x * 256 + threadIdx.x;
    if (i >= n4) return;
    const float4 f = reinterpret_cast<const float4*>(in)[i];
    const ushort_t h0 = f2bf(f.x), h1 = f2bf(f.y), h2 = f2bf(f.z), h3 = f2bf(f.w);
    ushort4 hv; hv.x = h0; hv.y = h1; hv.z = h2; hv.w = h3;
    ushort4 lv;
    lv.x = f2bf(f.x - bf2f(h0)); lv.y = f2bf(f.y - bf2f(h1));
    lv.z = f2bf(f.z - bf2f(h2)); lv.w = f2bf(f.w - bf2f(h3));
    reinterpret_cast<ushort4*>(hi)[i] = hv;
    reinterpret_cast<ushort4*>(lo)[i] = lv;
}

// ---------------------------------------------------------------------------
// 1. eta: one wave per (b,s) row, loops h=0..15. eta[((b*16+h)*128+n)*16+m]
// ---------------------------------------------------------------------------
__global__ __launch_bounds__(256) void eta_kernel(
    const float* __restrict__ x, const float* __restrict__ lrW,
    const float* __restrict__ lrb, const float* __restrict__ gsc,
    float* __restrict__ eta)
{
    const int row = blockIdx.x * 4 + (threadIdx.x >> 6);
    const int lane = threadIdx.x & 63;
    float xv[16];
#pragma unroll
    for (int i = 0; i < 16; ++i) xv[i] = x[(size_t)row * 1024 + lane + i * 64];
    const int b = row >> 11, s = row & 2047, n = s >> 4, m = s & 15;
    const float gs = fmaxf(1.0f / (float)(m + 1) + gsc[m], 0.0f);
    for (int h = 0; h < 16; ++h) {
        float acc = 0.0f;
#pragma unroll
        for (int i = 0; i < 16; ++i) acc += xv[i] * lrW[h * 1024 + lane + i * 64];
        acc = wave_sum(acc);
        if (lane == 0) {
            float sig = 1.0f / (1.0f + expf(-(acc + lrb[h])));
            eta[(((size_t)(b * 16 + h)) * 128 + n) * 16 + m] = (sig / 64.0f) * gs;
        }
    }
}

// ---------------------------------------------------------------------------
// Shared GEMM body (R5-verified): 512 threads, 128x128 tile, BK=32,
// vector-load + ds_write staging, one-tile register prefetch.
// ---------------------------------------------------------------------------
#define GEMM_TILE_BODY(Ah_g, Al_g, Bh_g, Bl_g, rowbase, colb)                  \
    __shared__ __align__(16) ushort_t Ash[128 * LSTRIDE];                      \
    __shared__ __align__(16) ushort_t Asl[128 * LSTRIDE];                      \
    __shared__ __align__(16) ushort_t Bsh[128 * LSTRIDE];                      \
    __shared__ __align__(16) ushort_t Bsl[128 * LSTRIDE];                      \
    const int tid = threadIdx.x;                                               \
    const int wv = tid >> 6, ln = tid & 63;                                    \
    const int l15 = ln & 15, lq = ln >> 4;                                     \
    const int wm = wv >> 2, wn = wv & 3;                                       \
    const int srow = tid >> 2;               /* 0..127 */                      \
    const int skseg = (tid & 3) * 8;         /* 0,8,16,24 */                   \
    const ushort_t* gA_h = (Ah_g) + (size_t)((rowbase) + srow) * 1024 + skseg; \
    const ushort_t* gA_l = (Al_g) + (size_t)((rowbase) + srow) * 1024 + skseg; \
    const ushort_t* gB_h = (Bh_g) + (size_t)((colb) + srow) * 1024 + skseg;    \
    const ushort_t* gB_l = (Bl_g) + (size_t)((colb) + srow) * 1024 + skseg;    \
    const int sw = srow * LSTRIDE + skseg;                                     \
    f32x4 acc[4][2] = {};                                                      \
    bf16x8 rAh = *reinterpret_cast<const bf16x8*>(gA_h);                       \
    bf16x8 rAl = *reinterpret_cast<const bf16x8*>(gA_l);                       \
    bf16x8 rBh = *reinterpret_cast<const bf16x8*>(gB_h);                       \
    bf16x8 rBl = *reinterpret_cast<const bf16x8*>(gB_l);                       \
    for (int k0 = 0; k0 < 1024; k0 += 32) {                                    \
        *reinterpret_cast<bf16x8*>(&Ash[sw]) = rAh;                            \
        *reinterpret_cast<bf16x8*>(&Asl[sw]) = rAl;                            \
        *reinterpret_cast<bf16x8*>(&Bsh[sw]) = rBh;                            \
        *reinterpret_cast<bf16x8*>(&Bsl[sw]) = rBl;                            \
        __syncthreads();                                                       \
        const int kn = k0 + 32;                                                \
        if (kn < 1024) {                                                       \
            rAh = *reinterpret_cast<const bf16x8*>(gA_h + kn);                 \
            rAl = *reinterpret_cast<const bf16x8*>(gA_l + kn);                 \
            rBh = *reinterpret_cast<const bf16x8*>(gB_h + kn);                 \
            rBl = *reinterpret_cast<const bf16x8*>(gB_l + kn);                 \
        }                                                                      \
        bf16x8 bh[2], bl[2];                                                   \
        _Pragma("unroll")                                                      \
        for (int u = 0; u < 2; ++u) {                                          \
            const int br = (wn * 32 + u * 16 + l15) * LSTRIDE + lq * 8;        \
            bh[u] = *reinterpret_cast<const bf16x8*>(&Bsh[br]);                \
            bl[u] = *reinterpret_cast<const bf16x8*>(&Bsl[br]);                \
        }                                                                      \
        _Pragma("unroll")                                                      \
        for (int t = 0; t < 4; ++t) {                                          \
            const int ar = (wm * 64 + t * 16 + l15) * LSTRIDE + lq * 8;        \
            const bf16x8 ah = *reinterpret_cast<const bf16x8*>(&Ash[ar]);      \
            const bf16x8 al = *reinterpret_cast<const bf16x8*>(&Asl[ar]);      \
            _Pragma("unroll")                                                  \
            for (int u = 0; u < 2; ++u) {                                      \
                acc[t][u] = __builtin_amdgcn_mfma_f32_16x16x32_bf16(ah, bh[u], acc[t][u], 0, 0, 0); \
                acc[t][u] = __builtin_amdgcn_mfma_f32_16x16x32_bf16(ah, bl[u], acc[t][u], 0, 0, 0); \
                acc[t][u] = __builtin_amdgcn_mfma_f32_16x16x32_bf16(al, bh[u], acc[t][u], 0, 0, 0); \
            }                                                                  \
        }                                                                      \
        __syncthreads();                                                       \
    }

// ---------------------------------------------------------------------------
// 2. QKV GEMM + RoPE. grid (64, 24), 512 threads.
// ---------------------------------------------------------------------------
__global__ __launch_bounds__(512) void qkv_rope_kernel(
    const ushort_t* __restrict__ xh, const ushort_t* __restrict__ xl,
    const ushort_t* __restrict__ Wqh, const ushort_t* __restrict__ Wql,
    const ushort_t* __restrict__ Wkh, const ushort_t* __restrict__ Wkl,
    const ushort_t* __restrict__ Wvh, const ushort_t* __restrict__ Wvl,
    const float* __restrict__ posf,
    float* __restrict__ Qb, float* __restrict__ Kb, float* __restrict__ Vb)
{
    const int rowbase = blockIdx.x * 128;
    const int colbase = blockIdx.y * 128;
    const int sel = colbase >> 10;                 // 0=Q 1=K 2=V (uniform)
    const ushort_t* WBh = (sel == 0) ? Wqh : (sel == 1) ? Wkh : Wvh;
    const ushort_t* WBl = (sel == 0) ? Wql : (sel == 1) ? Wkl : Wvl;
    float* dst = (sel == 0) ? Qb : (sel == 1) ? Kb : Vb;
    const int colm = colbase & 1023;

    GEMM_TILE_BODY(xh, xl, WBh, WBl, rowbase, colm)

    // epilogue: RoPE + scatter to [b][h][n][m][d]
#pragma unroll
    for (int t = 0; t < 4; ++t)
#pragma unroll
        for (int u = 0; u < 2; ++u) {
            const int col = colm + wn * 32 + u * 16 + l15;  // col in matrix
            const int d = col & 63, h = col >> 6;
            const int angidx = d >> 1;
            const int odd = d & 1;
#pragma unroll
            for (int r = 0; r < 4; ++r) {
                const int row = rowbase + wm * 64 + t * 16 + lq * 4 + r;
                const int b = row >> 11, s = row & 2047;
                const float ang = posf[s * 32 + angidx];
                const float c = cosf(ang), sn = sinf(ang);
                const float own = acc[t][u][r];
                const float partner = __shfl_xor(own, 1, 64);
                const float res = odd ? (partner * sn + own * c)
                                      : (own * c - partner * sn);
                const int n = s >> 4, m = s & 15;
                dst[(((size_t)(b * 16 + h)) * 128 + n) * 1024 + m * 64 + d] = res;
            }
        }
}

// ---------------------------------------------------------------------------
// 3. TTT scan: 64 blocks (one per (b,h)), 1024 threads (wave=m, lane=d).
//    R7/R8: DPP wave sums (1 LDS op per value), float4 cumsum phase.
//    Fused K-side algebra (R6, verified):
//      t1 = rstd*(C - mu*G) + SE
//      t2 = rstd^2*(D - 2mu*C + mu^2*G) + rstd*(F - mu*SE)
// ---------------------------------------------------------------------------
__global__ __launch_bounds__(1024) void scan_kernel(
    const float* __restrict__ Qb, const float* __restrict__ Kb,
    const float* __restrict__ Vb, const float* __restrict__ eta,
    const float* __restrict__ tg, const float* __restrict__ tb,
    const float* __restrict__ coeff, float* __restrict__ out_pre)
{
    __shared__ __align__(16) float Wl[12 * 64];   // rows 0..10 = W, row 11 = 0
    __shared__ __align__(16) float cum[16 * 12 * 64];

    const int tid = threadIdx.x;
    const int m = tid >> 6, d = tid & 63;
    const int b = blockIdx.x >> 4, h = blockIdx.x & 15;

    const float gam = tg[h * 64 + d];
    const float bet = tb[h * 64 + d];
    const float gam2 = gam * gam;
    const float G = wave_sum(gam2);

    if (tid < 768) Wl[tid] = (tid < 704) ? coeff[h * 704 + tid] : 0.0f;
    __syncthreads();

    const size_t base = ((size_t)(b * 16 + h)) * 131072;
    const float* Qp = Qb + base;
    const float* Kp = Kb + base;
    const float* Vp = Vb + base;
    const float* ep = eta + ((size_t)(b * 16 + h)) * 2048;

    float kf = Kp[tid], vf = Vp[tid], qf = Qp[tid], ei = ep[m];

    for (int n = 0; n < 128; ++n) {
        const int n1 = (n < 127) ? n + 1 : n;
        const float kfN = Kp[n1 * 1024 + tid];
        const float vfN = Vp[n1 * 1024 + tid];
        const float qfN = Qp[n1 * 1024 + tid];
        const float eiN = ep[n1 * 16 + m];

        // ---- K side ----
        const Bas4 bk = bspline4(kf);
        float zk = fast_silu(kf);
#pragma unroll
        for (int t = 0; t < 4; ++t)
            zk = fmaf(bk.n[t], Wl[bk.j[t] * 64 + d], zk);

        const float E = gam * (bet - (vf - kf));
        const float r0 = wave_sum(zk);
        const float r1 = wave_sum(zk * zk);
        const float r2 = wave_sum(gam2 * zk);
        const float r3 = wave_sum(gam2 * zk * zk);
        const float r4 = wave_sum(E);
        const float r5 = wave_sum(E * zk);

        const float mu = r0 * (1.0f / 64.0f);
        const float var = r1 * (1.0f / 64.0f) - mu * mu;
        const float rstd = fast_rsq(var + 1e-6f);
        const float xhat = (zk - mu) * rstd;
        const float gxh = gam2 * xhat + E;
        const float t1 = rstd * (r2 - mu * G) + r4;
        const float t2 = rstd * rstd * (r3 - 2.0f * mu * r2 + mu * mu * G)
                       + rstd * (r5 - mu * r4);
        const float gz = (gxh - t1 * (1.0f / 64.0f) - xhat * (t2 * (1.0f / 64.0f))) * rstd;

        // ---- tok scatter: zero 12 slots then overwrite the 4 live ones ----
        const float tokf = ei * gz;
#pragma unroll
        for (int j = 0; j < 12; ++j) cum[m * 768 + j * 64 + d] = 0.0f;
#pragma unroll
        for (int t = 0; t < 4; ++t)
            cum[m * 768 + bk.j[t] * 64 + d] = tokf * bk.n[t];
        __syncthreads();

        // ---- in-place U = W - cumsum, float4-vectorized (176 threads) ----
        if (tid < 176) {
            float4* c4 = (float4*)cum;          // [16][192]
            float4* w4 = (float4*)Wl;           // [192]
            float4 v[16];
#pragma unroll
            for (int mm = 0; mm < 16; ++mm) v[mm] = c4[mm * 192 + tid];
            float4 a = w4[tid];
#pragma unroll
            for (int mm = 0; mm < 16; ++mm) {
                a.x -= v[mm].x; a.y -= v[mm].y; a.z -= v[mm].z; a.w -= v[mm].w;
                c4[mm * 192 + tid] = a;
            }
            w4[tid] = a;
        }
        __syncthreads();

        // ---- Q side ----
        const Bas4 bq = bspline4(qf);
        float zq = fast_silu(qf);
#pragma unroll
        for (int t = 0; t < 4; ++t)
            zq = fmaf(bq.n[t], cum[m * 768 + bq.j[t] * 64 + d], zq);

        const float u1 = wave_sum(zq);
        const float u2 = wave_sum(zq * zq);
        const float mu2 = u1 * (1.0f / 64.0f);
        const float var2 = u2 * (1.0f / 64.0f) - mu2 * mu2;
        const float rstd2 = fast_rsq(var2 + 1e-6f);
        const float y = qf + gam * (zq - mu2) * rstd2 + bet;
        out_pre[((size_t)b * 2048 + n * 16 + m) * 1024 + h * 64 + d] = y;

        __syncthreads();
        kf = kfN; vf = vfN; qf = qfN; ei = eiN;
    }
}

// ---------------------------------------------------------------------------
// 4. Final LayerNorm over DIM=1024 -> (hi, lo) bf16 for the split out-GEMM.
// ---------------------------------------------------------------------------
__global__ __launch_bounds__(256) void ln_kernel(
    const float* __restrict__ in, const float* __restrict__ pw,
    const float* __restrict__ pb, ushort_t* __restrict__ hi,
    ushort_t* __restrict__ lo)
{
    const int row = blockIdx.x * 4 + (threadIdx.x >> 6);
    const int lane = threadIdx.x & 63;
    const float* r = in + (size_t)row * 1024;
    float v[16];
    float s1 = 0.0f, s2 = 0.0f;
#pragma unroll
    for (int i = 0; i < 16; ++i) {
        v[i] = r[lane + i * 64];
        s1 += v[i];
        s2 += v[i] * v[i];
    }
    s1 = wave_sum(s1);
    s2 = wave_sum(s2);
    const float mu = s1 * (1.0f / 1024.0f);
    const float var = s2 * (1.0f / 1024.0f) - mu * mu;
    const float rstd = rsqrtf(var + 1e-6f);
#pragma unroll
    for (int i = 0; i < 16; ++i) {
        const int c = lane + i * 64;
        const float o = (v[i] - mu) * rstd * pw[c] + pb[c];
        const ushort_t h = f2bf(o);
        hi[(size_t)row * 1024 + c] = h;
        lo[(size_t)row * 1024 + c] = f2bf(o - bf2f(h));
    }
}

// ---------------------------------------------------------------------------
// 5. Output GEMM: same skeleton; plain fp32 epilogue. grid (64, 8).
// ---------------------------------------------------------------------------
__global__ __launch_bounds__(512) void out_gemm_kernel(
    const ushort_t* __restrict__ Ahg, const ushort_t* __restrict__ Alg,
    const ushort_t* __restrict__ Bhg, const ushort_t* __restrict__ Blg,
    float* __restrict__ out)
{
    const int rowbase = blockIdx.x * 128;
    const int colbase = blockIdx.y * 128;

    GEMM_TILE_BODY(Ahg, Alg, Bhg, Blg, rowbase, colbase)

#pragma unroll
    for (int t = 0; t < 4; ++t)
#pragma unroll
        for (int u = 0; u < 2; ++u) {
            const int col = colbase + wn * 32 + u * 16 + l15;
#pragma unroll
            for (int r = 0; r < 4; ++r) {
                const int row = rowbase + wm * 64 + t * 16 + lq * 4 + r;
                out[(size_t)row * 1024 + col] = acc[t][u][r];
            }
        }
}

// ---------------------------------------------------------------------------
extern "C" void kernel_launch(void* const* d_in, const int* in_sizes, int n_in,
                              void* d_out, int out_size, void* d_ws, size_t ws_size,
                              hipStream_t stream) {
    const float* x    = (const float*)d_in[0];
    const float* posf = (const float*)d_in[1];
    const float* Wq   = (const float*)d_in[2];
    const float* Wk   = (const float*)d_in[3];
    const float* Wv   = (const float*)d_in[4];
    const float* Wo   = (const float*)d_in[5];
    const float* lrW  = (const float*)d_in[6];
    const float* lrb  = (const float*)d_in[7];
    const float* gsc  = (const float*)d_in[8];
    const float* tg   = (const float*)d_in[9];
    const float* tb   = (const float*)d_in[10];
    const float* pw   = (const float*)d_in[11];
    const float* pb   = (const float*)d_in[12];
    const float* coeff= (const float*)d_in[13];
    // d_in[14] = knots: uniform linspace(-1,1,15); closed-form in scan.

    char* ws = (char*)d_ws;
    float*    Qb   = (float*)(ws);                      // 32 MB [dead after scan]
    float*    Kb   = (float*)(ws + 33554432);           // 32 MB [dead after scan]
    float*    Vb   = (float*)(ws + 67108864);           // 32 MB
    ushort_t* xh   = (ushort_t*)(ws + 100663296);       // 16 MB [dead after qkv]
    ushort_t* xl   = (ushort_t*)(ws + 117440512);       // 16 MB
    float*    outp = (float*)(ws + 100663296);          // 32 MB (aliases xh+xl)
    float*    eta  = (float*)(ws + 134217728);          // 0.5 MB
    ushort_t* Wqh  = (ushort_t*)(ws + 134742016);       // 2 MB each
    ushort_t* Wql  = (ushort_t*)(ws + 136839168);
    ushort_t* Wkh  = (ushort_t*)(ws + 138936320);
    ushort_t* Wkl  = (ushort_t*)(ws + 141033472);
    ushort_t* Wvh  = (ushort_t*)(ws + 143130624);
    ushort_t* Wvl  = (ushort_t*)(ws + 145227776);
    ushort_t* Woh  = (ushort_t*)(ws + 147324928);
    ushort_t* Wol  = (ushort_t*)(ws + 149422080);       // end 151519232
    ushort_t* lnh  = (ushort_t*)(ws);                   // aliases Qb (dead)
    ushort_t* lnl  = (ushort_t*)(ws + 16777216);

    split_kernel<<<8192, 256, 0, stream>>>(x,  xh,  xl,  2097152);
    split_kernel<<<1024, 256, 0, stream>>>(Wq, Wqh, Wql, 262144);
    split_kernel<<<1024, 256, 0, stream>>>(Wk, Wkh, Wkl, 262144);
    split_kernel<<<1024, 256, 0, stream>>>(Wv, Wvh, Wvl, 262144);
    split_kernel<<<1024, 256, 0, stream>>>(Wo, Woh, Wol, 262144);
    eta_kernel<<<2048, 256, 0, stream>>>(x, lrW, lrb, gsc, eta);
    qkv_rope_kernel<<<dim3(64, 24), 512, 0, stream>>>(xh, xl, Wqh, Wql, Wkh, Wkl,
                                                      Wvh, Wvl, posf, Qb, Kb, Vb);
    scan_kernel<<<64, 1024, 0, stream>>>(Qb, Kb, Vb, eta, tg, tb, coeff, outp);
    ln_kernel<<<2048, 256, 0, stream>>>(outp, pw, pb, lnh, lnl);
    out_gemm_kernel<<<dim3(64, 8), 512, 0, stream>>>(lnh, lnl, Woh, Wol, (float*)d_out);
}